// Round 1
// baseline (111.103 us; speedup 1.0000x reference)
//
#include <hip/hip_runtime.h>
#include <math.h>
#include <stdint.h>

// ---------------- problem constants ----------------
#define NNODES 512
#define FEAT   128
#define NR     300
#define NC     25
#define NB     180
#define NA     360
// output layout: type_dist[6] | radial_probs[300] | angular[64800] | radius | y | alpha
#define O_TYPE   0
#define O_RAD    6
#define O_ANG    306
#define O_RADIUS 65106
#define O_Y      65107
#define O_ALPHA  65108

// ---------------- workspace layout (float indices) ----------------
#define WS_KEYS   0     // 4 uints: k_r(2), k_a(2)
#define WS_FOCUS  4     // int
#define WS_TYPEI  5     // int
#define WS_RIDX   6     // int
#define WS_LOGZ   7     // float
#define WS_LR     16    // 300 floats
#define WS_SCORES 320   // 512
#define WS_POSIN  832   // 256
#define WS_PSUM   1088  // 180
#define WS_PV     1280  // 180
#define WS_PI     1472  // 180 ints
#define WS_Q      1664  // 180*25 = 4500
#define WS_HR     6176  // 180*12 = 2160 (16B aligned: 6176*4 % 16 == 0)
#define WS_COEF   8352  // 7500
// total ~15852 floats (~64 KB)

// m value per SH column c (l = 0..4, m = -l..l, c = l*l + l + m)
__constant__ int c_m_of_c[25] = {0,-1,0,1,-2,-1,0,1,2,-3,-2,-1,0,1,2,3,-4,-3,-2,-1,0,1,2,3,4};
// Fourier-coefficient term lists: jj=0..4 -> cos m=0..4 ; jj=5..8 -> sin m=1..4
__constant__ int c_h_cnt[9] = {5,4,3,2,1,4,3,2,1};
__constant__ int c_h_idx[9][5] = {
  {0,2,6,12,20},
  {3,7,13,21,0},
  {8,14,22,0,0},
  {15,23,0,0,0},
  {24,0,0,0,0},
  {1,5,11,19,0},
  {4,10,18,0,0},
  {9,17,0,0,0},
  {16,0,0,0,0}};

// ---------------- threefry2x32 (JAX semantics) ----------------
__device__ __forceinline__ void tf2x32(uint32_t k0, uint32_t k1, uint32_t x0, uint32_t x1,
                                       uint32_t& o0, uint32_t& o1) {
  uint32_t ks2 = k0 ^ k1 ^ 0x1BD11BDAu;
#define TF_RND(r) { x0 += x1; x1 = (x1 << r) | (x1 >> (32 - r)); x1 ^= x0; }
  x0 += k0; x1 += k1;
  TF_RND(13) TF_RND(15) TF_RND(26) TF_RND(6)
  x0 += k1; x1 += ks2 + 1u;
  TF_RND(17) TF_RND(29) TF_RND(16) TF_RND(24)
  x0 += ks2; x1 += k0 + 2u;
  TF_RND(13) TF_RND(15) TF_RND(26) TF_RND(6)
  x0 += k0; x1 += k1 + 3u;
  TF_RND(17) TF_RND(29) TF_RND(16) TF_RND(24)
  x0 += k1; x1 += ks2 + 4u;
  TF_RND(13) TF_RND(15) TF_RND(26) TF_RND(6)
  x0 += ks2; x1 += k0 + 5u;
#undef TF_RND
  o0 = x0; o1 = x1;
}

// partitionable-mode 32-bit random bits for 64-bit counter (hi=0, lo=i): word0 ^ word1
__device__ __forceinline__ float gumbel32(uint32_t k0, uint32_t k1, uint32_t lo) {
  uint32_t o0, o1; tf2x32(k0, k1, 0u, lo, o0, o1);
  uint32_t bits = o0 ^ o1;
  float u = __uint_as_float((bits >> 9) | 0x3f800000u) - 1.0f;   // [0,1)
  u = fmaxf(u, 1.1754944e-38f);                                   // minval = tiny
  return -logf(-logf(u));
}

// ---------------- K0: Q extraction + PRNG keys ----------------
__global__ __launch_bounds__(256) void k_prep(const float* __restrict__ basis,
                                              const float* __restrict__ alpha_grid,
                                              float* __restrict__ wsf) {
  int t = blockIdx.x * 256 + threadIdx.x;
  if (blockIdx.x == 0 && threadIdx.x == 0) {
    uint32_t* wu = (uint32_t*)wsf;
    uint32_t o0, o1;
    tf2x32(0u, 42u, 0u, 0u, o0, o1); wu[WS_KEYS + 0] = o0; wu[WS_KEYS + 1] = o1; // k_r
    tf2x32(0u, 42u, 0u, 1u, o0, o1); wu[WS_KEYS + 2] = o0; wu[WS_KEYS + 3] = o1; // k_a
  }
  if (t < NB * NC) {
    int b = t / NC, c = t % NC;
    int m = c_m_of_c[c];
    float q;
    if (m >= 0) {
      q = basis[(b * NA + 0) * NC + c];                 // cos(0)=1
    } else {
      float a10 = alpha_grid[10];
      q = basis[(b * NA + 10) * NC + c] / sinf((float)(-m) * a10);
    }
    wsf[WS_Q + t] = q;
  }
}

// ---------------- K1: focus MLP (relu), scores[512] ----------------
__global__ __launch_bounds__(128) void k_focus(const float* __restrict__ x,
    const float* __restrict__ w1, const float* __restrict__ w2, const float* __restrict__ w3,
    const float* __restrict__ w4, const float* __restrict__ w5, float* __restrict__ wsf) {
  __shared__ float ha[128], hb[128];
  int n = blockIdx.x, j = threadIdx.x;
  ha[j] = x[n * FEAT + j];
  __syncthreads();
  float acc = 0.f;
#pragma unroll 8
  for (int k = 0; k < 128; k++) acc += ha[k] * w1[k * 128 + j];
  hb[j] = fmaxf(acc, 0.f);
  __syncthreads();
  acc = 0.f;
#pragma unroll 8
  for (int k = 0; k < 128; k++) acc += hb[k] * w2[k * 128 + j];
  ha[j] = fmaxf(acc, 0.f);
  __syncthreads();
  if (j < 64) {
    acc = 0.f;
#pragma unroll 8
    for (int k = 0; k < 128; k++) acc += ha[k] * w3[k * 64 + j];
    hb[j] = fmaxf(acc, 0.f);
  }
  __syncthreads();
  if (j < 16) {
    acc = 0.f;
#pragma unroll
    for (int k = 0; k < 64; k++) acc += hb[k] * w4[k * 16 + j];
    ha[j] = fmaxf(acc, 0.f);
  }
  __syncthreads();
  if (j == 0) {
    acc = 0.f;
#pragma unroll
    for (int k = 0; k < 16; k++) acc += ha[k] * w5[k * 2 + 0];
    wsf[WS_SCORES + n] = acc;
  }
}

// ---------------- K2: focus argmax over 513 (scores ++ [0]) ----------------
__global__ __launch_bounds__(256) void k_focus_argmax(float* __restrict__ wsf) {
  __shared__ float rv[256]; __shared__ int ri[256];
  int t = threadIdx.x;
  float bv = -INFINITY; int bi = 1 << 30;
  for (int i = t; i < NNODES + 1; i += 256) {
    float v = (i < NNODES) ? wsf[WS_SCORES + i] : 0.f;
    if (v > bv || (v == bv && i < bi)) { bv = v; bi = i; }
  }
  rv[t] = bv; ri[t] = bi; __syncthreads();
  for (int s = 128; s > 0; s >>= 1) {
    if (t < s) {
      float v2 = rv[t + s]; int i2 = ri[t + s];
      if (v2 > rv[t] || (v2 == rv[t] && i2 < ri[t])) { rv[t] = v2; ri[t] = i2; }
    }
    __syncthreads();
  }
  if (t == 0) ((int*)wsf)[WS_FOCUS] = (ri[0] < NNODES - 1) ? ri[0] : (NNODES - 1);
}

// ---------------- K3: type MLP (softplus) + type_dist + pos_in ----------------
__global__ __launch_bounds__(128) void k_type(const float* __restrict__ x,
    const float* __restrict__ w1, const float* __restrict__ w2, const float* __restrict__ w3,
    const float* __restrict__ w4, const float* __restrict__ w5, const float* __restrict__ w6,
    const float* __restrict__ type_emb, float* __restrict__ out, float* __restrict__ wsf) {
  __shared__ float ha[128], hb[128];
  __shared__ float lg[6];
  __shared__ int ti_sh;
  int j = threadIdx.x;
  int focus = ((const int*)wsf)[WS_FOCUS];
  float xv = x[focus * FEAT + j];
  ha[j] = xv;
  wsf[WS_POSIN + j] = xv;
  __syncthreads();
  const float* Ws[5] = {w1, w2, w3, w4, w5};
#pragma unroll
  for (int L = 0; L < 5; L++) {
    const float* W = Ws[L];
    const float* src = (L & 1) ? hb : ha;
    float* dst = (L & 1) ? ha : hb;
    float acc = 0.f;
#pragma unroll 8
    for (int k = 0; k < 128; k++) acc += src[k] * W[k * 128 + j];
    dst[j] = fmaxf(acc, 0.f) + log1pf(expf(-fabsf(acc)));  // softplus = logaddexp(x,0)
    __syncthreads();
  }
  // final hidden is in hb (L=4 wrote dst=hb)
  if (j < 6) {
    float acc = 0.f;
#pragma unroll 8
    for (int k = 0; k < 128; k++) acc += hb[k] * w6[k * 6 + j];
    lg[j] = acc;
  }
  __syncthreads();
  if (j == 0) {
    float M = lg[0]; int am = 0;
    for (int i = 1; i < 6; i++) if (lg[i] > M) { M = lg[i]; am = i; }
    float e[6], S = 0.f;
    for (int i = 0; i < 6; i++) { e[i] = expf(lg[i] - M); S += e[i]; }
    for (int i = 0; i < 6; i++) out[O_TYPE + i] = e[i] / S;
    int ti = (am < 4) ? am : 4;
    ((int*)wsf)[WS_TYPEI] = ti;
    ti_sh = ti;
  }
  __syncthreads();
  wsf[WS_POSIN + 128 + j] = type_emb[ti_sh * FEAT + j];
}

// ---------------- K4: coeffs = pos_in @ pos_w ----------------
__global__ __launch_bounds__(256) void k_coeffs(const float* __restrict__ pos_w,
                                                float* __restrict__ wsf) {
  __shared__ float pin[256];
  int t = threadIdx.x;
  pin[t] = wsf[WS_POSIN + t];
  __syncthreads();
  int o = blockIdx.x * 256 + t;
  if (o < NR * NC) {
    float acc = 0.f;
#pragma unroll 8
    for (int k = 0; k < 256; k++) acc += pin[k] * pos_w[k * (NR * NC) + o];
    wsf[WS_COEF + o] = acc;
  }
}

// ---------------- K6: per-radius logsumexp over the sphere ----------------
__global__ __launch_bounds__(384) void k_radial_lse(const float* __restrict__ qw,
    const float* __restrict__ alpha_grid, float* __restrict__ wsf) {
  __shared__ float4 Hs4[NB * 3];      // 180 rows x 12 floats
  __shared__ float cs[NC];
  __shared__ float lms[NB];
  __shared__ float red[512];
  int r = blockIdx.x, t = threadIdx.x;
  float* Hs = (float*)Hs4;
  if (t < NC) cs[t] = wsf[WS_COEF + r * NC + t];
  for (int i = t; i < NB; i += 384)
    lms[i] = logf(qw[i]) + logf(6.28318530717958647692f / 360.0f);
  __syncthreads();
  for (int p = t; p < NB * 9; p += 384) {
    int b = p / 9, jj = p % 9;
    int n = c_h_cnt[jj];
    float acc = 0.f;
    for (int q = 0; q < n; q++) { int c = c_h_idx[jj][q]; acc += cs[c] * wsf[WS_Q + b * NC + c]; }
    if (jj == 0) acc += lms[b];     // fold log-measure into the m=0 (T=1) term
    Hs[b * 12 + jj] = acc;
  }
  __syncthreads();
  int a = t;
  float c1 = 0, c2 = 0, c3 = 0, c4 = 0, s1 = 0, s2 = 0, s3 = 0, s4 = 0;
  if (a < NA) {
    float al = alpha_grid[a];
    sincosf(al, &s1, &c1);
    sincosf(2.f * al, &s2, &c2);
    sincosf(3.f * al, &s3, &c3);
    sincosf(4.f * al, &s4, &c4);
  }
  float acc = 0.f;
  for (int b = 0; b < NB; b++) {
    float4 h0 = Hs4[b * 3 + 0], h1 = Hs4[b * 3 + 1], h2 = Hs4[b * 3 + 2];
    float f = h0.x + h0.y * c1 + h0.z * c2 + h0.w * c3 + h1.x * c4
            + h1.y * s1 + h1.z * s2 + h1.w * s3 + h2.x * s4;
    if (a < NA) acc += expf(f);
  }
  red[t] = acc;
  if (t < 128) red[384 + t] = 0.f;
  __syncthreads();
  for (int s = 256; s > 0; s >>= 1) { if (t < s) red[t] += red[t + s]; __syncthreads(); }
  if (t == 0) wsf[WS_LR + r] = logf(red[0]);
}

// ---------------- K7: radial softmax + categorical sample + Hr ----------------
__global__ __launch_bounds__(256) void k_radial_sample(float* __restrict__ out,
                                                       float* __restrict__ wsf) {
  __shared__ float red[256]; __shared__ int ri[256];
  __shared__ float Msh, Ssh; __shared__ int rsh;
  int t = threadIdx.x;
  const uint32_t* wu = (const uint32_t*)wsf;
  uint32_t kr0 = wu[WS_KEYS + 0], kr1 = wu[WS_KEYS + 1];
  float m = -INFINITY;
  for (int i = t; i < NR; i += 256) m = fmaxf(m, wsf[WS_LR + i]);
  red[t] = m; __syncthreads();
  for (int s = 128; s > 0; s >>= 1) { if (t < s) red[t] = fmaxf(red[t], red[t + s]); __syncthreads(); }
  if (t == 0) Msh = red[0];
  __syncthreads();
  float M = Msh;
  float ss = 0.f;
  for (int i = t; i < NR; i += 256) ss += expf(wsf[WS_LR + i] - M);
  __syncthreads();
  red[t] = ss; __syncthreads();
  for (int s = 128; s > 0; s >>= 1) { if (t < s) red[t] += red[t + s]; __syncthreads(); }
  if (t == 0) Ssh = red[0];
  __syncthreads();
  float S = Ssh;
  for (int i = t; i < NR; i += 256) out[O_RAD + i] = expf(wsf[WS_LR + i] - M) / S;
  // gumbel-argmax categorical over log_radial
  float bv = -INFINITY; int bi = 1 << 30;
  for (int i = t; i < NR; i += 256) {
    float v = wsf[WS_LR + i] + gumbel32(kr0, kr1, (uint32_t)i);
    if (v > bv || (v == bv && i < bi)) { bv = v; bi = i; }
  }
  __syncthreads();
  red[t] = bv; ri[t] = bi; __syncthreads();
  for (int s = 128; s > 0; s >>= 1) {
    if (t < s) {
      float v2 = red[t + s]; int i2 = ri[t + s];
      if (v2 > red[t] || (v2 == red[t] && i2 < ri[t])) { red[t] = v2; ri[t] = i2; }
    }
    __syncthreads();
  }
  if (t == 0) {
    int r = ri[0];
    rsh = r;
    ((int*)wsf)[WS_RIDX] = r;
    out[O_RADIUS] = (float)(r + 1) * 0.05f;
  }
  __syncthreads();
  int r = rsh;
  for (int p = t; p < NB * 9; p += 256) {
    int b = p / 9, jj = p % 9, n = c_h_cnt[jj];
    float acc = 0.f;
    for (int q = 0; q < n; q++) {
      int c = c_h_idx[jj][q];
      acc += wsf[WS_COEF + r * NC + c] * wsf[WS_Q + b * NC + c];
    }
    wsf[WS_HR + b * 12 + jj] = acc;   // NOTE: no log-measure folded here
  }
}

// ---------------- K8a: per-beta partial Z and partial gumbel-argmax ----------------
__global__ __launch_bounds__(384) void k_ang_partial(const float* __restrict__ qw,
    const float* __restrict__ alpha_grid, float* __restrict__ wsf) {
  __shared__ float red[512]; __shared__ int ri[512];
  int b = blockIdx.x, t = threadIdx.x;
  const uint32_t* wu = (const uint32_t*)wsf;
  uint32_t ka0 = wu[WS_KEYS + 2], ka1 = wu[WS_KEYS + 3];
  const float4* hr4 = (const float4*)(wsf + WS_HR + b * 12);
  float4 h0 = hr4[0], h1 = hr4[1], h2 = hr4[2];
  float lm = logf(qw[b]) + logf(6.28318530717958647692f / 360.0f);
  float e = 0.f, v = -INFINITY; int idx = b * NA + t;
  if (t < NA) {
    float al = alpha_grid[t];
    float s1, c1, s2, c2, s3, c3, s4, c4;
    sincosf(al, &s1, &c1); sincosf(2.f * al, &s2, &c2);
    sincosf(3.f * al, &s3, &c3); sincosf(4.f * al, &s4, &c4);
    float f = h0.x + h0.y * c1 + h0.z * c2 + h0.w * c3 + h1.x * c4
            + h1.y * s1 + h1.z * s2 + h1.w * s3 + h2.x * s4;
    float fl = f + lm;
    e = expf(fl);
    v = fl + gumbel32(ka0, ka1, (uint32_t)idx);
  }
  red[t] = e; if (t < 128) red[384 + t] = 0.f;
  __syncthreads();
  for (int s = 256; s > 0; s >>= 1) { if (t < s) red[t] += red[t + s]; __syncthreads(); }
  if (t == 0) wsf[WS_PSUM + b] = red[0];
  __syncthreads();
  red[t] = v; ri[t] = idx;
  if (t < 128) { red[384 + t] = -INFINITY; ri[384 + t] = 1 << 30; }
  __syncthreads();
  for (int s = 256; s > 0; s >>= 1) {
    if (t < s) {
      float v2 = red[t + s]; int i2 = ri[t + s];
      if (v2 > red[t] || (v2 == red[t] && i2 < ri[t])) { red[t] = v2; ri[t] = i2; }
    }
    __syncthreads();
  }
  if (t == 0) { wsf[WS_PV + b] = red[0]; ((int*)wsf)[WS_PI + b] = ri[0]; }
}

// ---------------- K8b: logZr + final angular argmax -> y/alpha outputs ----------------
__global__ __launch_bounds__(256) void k_ang_final(const float* __restrict__ y_grid,
    const float* __restrict__ alpha_grid, float* __restrict__ out, float* __restrict__ wsf) {
  __shared__ float red[256]; __shared__ int ri[256];
  int t = threadIdx.x;
  float sv = (t < NB) ? wsf[WS_PSUM + t] : 0.f;
  red[t] = sv; __syncthreads();
  for (int s = 128; s > 0; s >>= 1) { if (t < s) red[t] += red[t + s]; __syncthreads(); }
  if (t == 0) wsf[WS_LOGZ] = logf(red[0]);
  __syncthreads();
  float v = (t < NB) ? wsf[WS_PV + t] : -INFINITY;
  int i = (t < NB) ? ((const int*)wsf)[WS_PI + t] : (1 << 30);
  red[t] = v; ri[t] = i; __syncthreads();
  for (int s = 128; s > 0; s >>= 1) {
    if (t < s) {
      float v2 = red[t + s]; int i2 = ri[t + s];
      if (v2 > red[t] || (v2 == red[t] && i2 < ri[t])) { red[t] = v2; ri[t] = i2; }
    }
    __syncthreads();
  }
  if (t == 0) {
    int idx = ri[0];
    int yi = idx / NA, ai = idx % NA;
    out[O_Y] = y_grid[yi];
    out[O_ALPHA] = alpha_grid[ai];
  }
}

// ---------------- K8c: angular_dist = exp(fr - logZr) ----------------
__global__ __launch_bounds__(384) void k_ang_write(const float* __restrict__ alpha_grid,
    float* __restrict__ out, float* __restrict__ wsf) {
  int b = blockIdx.x, t = threadIdx.x;
  if (t >= NA) return;
  const float4* hr4 = (const float4*)(wsf + WS_HR + b * 12);
  float4 h0 = hr4[0], h1 = hr4[1], h2 = hr4[2];
  float logZ = wsf[WS_LOGZ];
  float al = alpha_grid[t];
  float s1, c1, s2, c2, s3, c3, s4, c4;
  sincosf(al, &s1, &c1); sincosf(2.f * al, &s2, &c2);
  sincosf(3.f * al, &s3, &c3); sincosf(4.f * al, &s4, &c4);
  float f = h0.x + h0.y * c1 + h0.z * c2 + h0.w * c3 + h1.x * c4
          + h1.y * s1 + h1.z * s2 + h1.w * s3 + h2.x * s4;
  out[O_ANG + b * NA + t] = expf(f - logZ);
}

// ---------------- launch ----------------
extern "C" void kernel_launch(void* const* d_in, const int* in_sizes, int n_in,
                              void* d_out, int out_size, void* d_ws, size_t ws_size,
                              hipStream_t stream) {
  const float* x          = (const float*)d_in[0];
  const float* fw1        = (const float*)d_in[1];
  const float* fw2        = (const float*)d_in[2];
  const float* fw3        = (const float*)d_in[3];
  const float* fw4        = (const float*)d_in[4];
  const float* fw5        = (const float*)d_in[5];
  const float* tw1        = (const float*)d_in[6];
  const float* tw2        = (const float*)d_in[7];
  const float* tw3        = (const float*)d_in[8];
  const float* tw4        = (const float*)d_in[9];
  const float* tw5        = (const float*)d_in[10];
  const float* tw6        = (const float*)d_in[11];
  const float* pos_w      = (const float*)d_in[12];
  const float* type_emb   = (const float*)d_in[13];
  const float* basis      = (const float*)d_in[14];
  const float* qw         = (const float*)d_in[15];
  const float* y_grid     = (const float*)d_in[16];
  const float* alpha_grid = (const float*)d_in[17];
  (void)in_sizes; (void)n_in; (void)out_size; (void)ws_size;
  float* out = (float*)d_out;
  float* wsf = (float*)d_ws;

  k_prep<<<18, 256, 0, stream>>>(basis, alpha_grid, wsf);
  k_focus<<<NNODES, 128, 0, stream>>>(x, fw1, fw2, fw3, fw4, fw5, wsf);
  k_focus_argmax<<<1, 256, 0, stream>>>(wsf);
  k_type<<<1, 128, 0, stream>>>(x, tw1, tw2, tw3, tw4, tw5, tw6, type_emb, out, wsf);
  k_coeffs<<<30, 256, 0, stream>>>(pos_w, wsf);
  k_radial_lse<<<NR, 384, 0, stream>>>(qw, alpha_grid, wsf);
  k_radial_sample<<<1, 256, 0, stream>>>(out, wsf);
  k_ang_partial<<<NB, 384, 0, stream>>>(qw, alpha_grid, wsf);
  k_ang_final<<<1, 256, 0, stream>>>(y_grid, alpha_grid, out, wsf);
  k_ang_write<<<NB, 384, 0, stream>>>(alpha_grid, out, wsf);
}

// Round 2
// 74.921 us; speedup vs baseline: 1.4829x; 1.4829x over previous
//
#include <hip/hip_runtime.h>
#include <math.h>
#include <stdint.h>

// ---------------- problem constants ----------------
#define NNODES 512
#define FEAT   128
#define NR     300
#define NC     25
#define NB     180
#define NA     360
#define RSPLIT 4
#define BCHUNK (NB / RSPLIT)   // 45
// output layout: type_dist[6] | radial_probs[300] | angular[64800] | radius | y | alpha
#define O_TYPE   0
#define O_RAD    6
#define O_ANG    306
#define O_RADIUS 65106
#define O_Y      65107
#define O_ALPHA  65108

// ---------------- workspace layout (float indices) ----------------
#define WS_KEYS   0     // 4 uints: k_r(2), k_a(2)
#define WS_FOCUS  4     // int
#define WS_TYPEI  5     // int
#define WS_RIDX   6     // int
#define WS_INVZ   7     // float (1/Z of angular dist)
#define WS_SCORES 320   // 512
#define WS_POSIN  832   // 256
#define WS_PSUM   1088  // 180
#define WS_PV     1280  // 180
#define WS_PI     1472  // 180 ints
#define WS_Q      1664  // 180*25 = 4500
#define WS_HR     6176  // 180*12 = 2160 (16B aligned)
#define WS_COEF   8352  // 7500
#define WS_LRP    15872 // 300*4 partial sphere sums
// total ~17072 floats (~68 KB)

// m value per SH column c (l = 0..4, m = -l..l, c = l*l + l + m)
__constant__ int c_m_of_c[25] = {0,-1,0,1,-2,-1,0,1,2,-3,-2,-1,0,1,2,3,-4,-3,-2,-1,0,1,2,3,4};
// Fourier-coefficient term lists: jj=0..4 -> cos m=0..4 ; jj=5..8 -> sin m=1..4
__constant__ int c_h_cnt[9] = {5,4,3,2,1,4,3,2,1};
__constant__ int c_h_idx[9][5] = {
  {0,2,6,12,20},
  {3,7,13,21,0},
  {8,14,22,0,0},
  {15,23,0,0,0},
  {24,0,0,0,0},
  {1,5,11,19,0},
  {4,10,18,0,0},
  {9,17,0,0,0},
  {16,0,0,0,0}};

// ---------------- threefry2x32 (JAX semantics) ----------------
__device__ __forceinline__ void tf2x32(uint32_t k0, uint32_t k1, uint32_t x0, uint32_t x1,
                                       uint32_t& o0, uint32_t& o1) {
  uint32_t ks2 = k0 ^ k1 ^ 0x1BD11BDAu;
#define TF_RND(r) { x0 += x1; x1 = (x1 << r) | (x1 >> (32 - r)); x1 ^= x0; }
  x0 += k0; x1 += k1;
  TF_RND(13) TF_RND(15) TF_RND(26) TF_RND(6)
  x0 += k1; x1 += ks2 + 1u;
  TF_RND(17) TF_RND(29) TF_RND(16) TF_RND(24)
  x0 += ks2; x1 += k0 + 2u;
  TF_RND(13) TF_RND(15) TF_RND(26) TF_RND(6)
  x0 += k0; x1 += k1 + 3u;
  TF_RND(17) TF_RND(29) TF_RND(16) TF_RND(24)
  x0 += k1; x1 += ks2 + 4u;
  TF_RND(13) TF_RND(15) TF_RND(26) TF_RND(6)
  x0 += ks2; x1 += k0 + 5u;
#undef TF_RND
  o0 = x0; o1 = x1;
}

// partitionable-mode 32-bit random bits for 64-bit counter (hi=0, lo=i): word0 ^ word1
__device__ __forceinline__ float gumbel32(uint32_t k0, uint32_t k1, uint32_t lo) {
  uint32_t o0, o1; tf2x32(k0, k1, 0u, lo, o0, o1);
  uint32_t bits = o0 ^ o1;
  float u = __uint_as_float((bits >> 9) | 0x3f800000u) - 1.0f;   // [0,1)
  u = fmaxf(u, 1.1754944e-38f);                                   // minval = tiny
  return -logf(-logf(u));
}

// ---------------- K1: focus MLP (relu) on blocks 0..511; prep on blocks 512+ ----------------
__global__ __launch_bounds__(128) void k_front(const float* __restrict__ x,
    const float* __restrict__ w1, const float* __restrict__ w2, const float* __restrict__ w3,
    const float* __restrict__ w4, const float* __restrict__ w5,
    const float* __restrict__ basis, const float* __restrict__ alpha_grid,
    float* __restrict__ wsf) {
  if (blockIdx.x >= NNODES) {
    // ---- prep role: Q extraction + PRNG keys ----
    int t = (blockIdx.x - NNODES) * 128 + threadIdx.x;
    if (blockIdx.x == NNODES && threadIdx.x == 0) {
      uint32_t* wu = (uint32_t*)wsf;
      uint32_t o0, o1;
      tf2x32(0u, 42u, 0u, 0u, o0, o1); wu[WS_KEYS + 0] = o0; wu[WS_KEYS + 1] = o1; // k_r
      tf2x32(0u, 42u, 0u, 1u, o0, o1); wu[WS_KEYS + 2] = o0; wu[WS_KEYS + 3] = o1; // k_a
    }
    if (t < NB * NC) {
      int b = t / NC, c = t % NC;
      int m = c_m_of_c[c];
      float q;
      if (m >= 0) {
        q = basis[(b * NA + 0) * NC + c];                 // cos(0)=1
      } else {
        float a10 = alpha_grid[10];
        q = basis[(b * NA + 10) * NC + c] / sinf((float)(-m) * a10);
      }
      wsf[WS_Q + t] = q;
    }
    return;
  }
  __shared__ float ha[128], hb[128];
  int n = blockIdx.x, j = threadIdx.x;
  ha[j] = x[n * FEAT + j];
  __syncthreads();
  float acc = 0.f;
#pragma unroll 8
  for (int k = 0; k < 128; k++) acc += ha[k] * w1[k * 128 + j];
  hb[j] = fmaxf(acc, 0.f);
  __syncthreads();
  acc = 0.f;
#pragma unroll 8
  for (int k = 0; k < 128; k++) acc += hb[k] * w2[k * 128 + j];
  ha[j] = fmaxf(acc, 0.f);
  __syncthreads();
  if (j < 64) {
    acc = 0.f;
#pragma unroll 8
    for (int k = 0; k < 128; k++) acc += ha[k] * w3[k * 64 + j];
    hb[j] = fmaxf(acc, 0.f);
  }
  __syncthreads();
  if (j < 16) {
    acc = 0.f;
#pragma unroll
    for (int k = 0; k < 64; k++) acc += hb[k] * w4[k * 16 + j];
    ha[j] = fmaxf(acc, 0.f);
  }
  __syncthreads();
  if (j == 0) {
    acc = 0.f;
#pragma unroll
    for (int k = 0; k < 16; k++) acc += ha[k] * w5[k * 2 + 0];
    wsf[WS_SCORES + n] = acc;
  }
}

// ---------------- K3: focus argmax + type MLP (softplus) + type_dist + pos_in ----------------
__global__ __launch_bounds__(128) void k_type(const float* __restrict__ x,
    const float* __restrict__ w1, const float* __restrict__ w2, const float* __restrict__ w3,
    const float* __restrict__ w4, const float* __restrict__ w5, const float* __restrict__ w6,
    const float* __restrict__ type_emb, float* __restrict__ out, float* __restrict__ wsf) {
  __shared__ float ha[128], hb[128];
  __shared__ float lg[6];
  __shared__ float av[2]; __shared__ int ai[2];
  __shared__ int ti_sh, f_sh;
  int j = threadIdx.x;
  // ---- argmax over 513 (scores ++ [0]) ----
  float bv = -INFINITY; int bi = 1 << 30;
  for (int i = j; i < NNODES + 1; i += 128) {
    float v = (i < NNODES) ? wsf[WS_SCORES + i] : 0.f;
    if (v > bv || (v == bv && i < bi)) { bv = v; bi = i; }
  }
  for (int off = 32; off; off >>= 1) {
    float v2 = __shfl_down(bv, off); int i2 = __shfl_down(bi, off);
    if (v2 > bv || (v2 == bv && i2 < bi)) { bv = v2; bi = i2; }
  }
  if ((j & 63) == 0) { av[j >> 6] = bv; ai[j >> 6] = bi; }
  __syncthreads();
  if (j == 0) {
    float v0 = av[0]; int i0 = ai[0];
    if (av[1] > v0 || (av[1] == v0 && ai[1] < i0)) { v0 = av[1]; i0 = ai[1]; }
    int focus = (i0 < NNODES - 1) ? i0 : (NNODES - 1);
    ((int*)wsf)[WS_FOCUS] = focus;
    f_sh = focus;
  }
  __syncthreads();
  int focus = f_sh;
  float xv = x[focus * FEAT + j];
  ha[j] = xv;
  wsf[WS_POSIN + j] = xv;
  __syncthreads();
  const float* Ws[5] = {w1, w2, w3, w4, w5};
#pragma unroll
  for (int L = 0; L < 5; L++) {
    const float* W = Ws[L];
    const float* src = (L & 1) ? hb : ha;
    float* dst = (L & 1) ? ha : hb;
    float acc = 0.f;
#pragma unroll 8
    for (int k = 0; k < 128; k++) acc += src[k] * W[k * 128 + j];
    dst[j] = fmaxf(acc, 0.f) + log1pf(expf(-fabsf(acc)));  // softplus = logaddexp(x,0)
    __syncthreads();
  }
  // final hidden is in hb (L=4 wrote dst=hb)
  if (j < 6) {
    float acc = 0.f;
#pragma unroll 8
    for (int k = 0; k < 128; k++) acc += hb[k] * w6[k * 6 + j];
    lg[j] = acc;
  }
  __syncthreads();
  if (j == 0) {
    float M = lg[0]; int am = 0;
    for (int i = 1; i < 6; i++) if (lg[i] > M) { M = lg[i]; am = i; }
    float e[6], S = 0.f;
    for (int i = 0; i < 6; i++) { e[i] = expf(lg[i] - M); S += e[i]; }
    for (int i = 0; i < 6; i++) out[O_TYPE + i] = e[i] / S;
    int ti = (am < 4) ? am : 4;
    ((int*)wsf)[WS_TYPEI] = ti;
    ti_sh = ti;
  }
  __syncthreads();
  wsf[WS_POSIN + 128 + j] = type_emb[ti_sh * FEAT + j];
}

// ---------------- K4: coeffs = pos_in @ pos_w (split-K, 64 outputs/block) ----------------
__global__ __launch_bounds__(256) void k_coeffs(const float* __restrict__ pos_w,
                                                float* __restrict__ wsf) {
  __shared__ float pin[256];
  __shared__ float partial[4][64];
  int t = threadIdx.x;
  pin[t] = wsf[WS_POSIN + t];
  __syncthreads();
  int oL = t & 63, kc = t >> 6;
  int o = blockIdx.x * 64 + oL;
  float acc = 0.f;
  if (o < NR * NC) {
#pragma unroll 16
    for (int k = 0; k < 64; k++) acc += pin[kc * 64 + k] * pos_w[(kc * 64 + k) * (NR * NC) + o];
  }
  partial[kc][oL] = acc;
  __syncthreads();
  if (kc == 0 && o < NR * NC)
    wsf[WS_COEF + o] = partial[0][oL] + partial[1][oL] + partial[2][oL] + partial[3][oL];
}

// ---------------- K6: per-(radius, beta-chunk) partial sphere sum ----------------
__global__ __launch_bounds__(384) void k_radial_lse(const float* __restrict__ qw,
    const float* __restrict__ alpha_grid, float* __restrict__ wsf) {
  __shared__ float4 Hs4[BCHUNK * 3];      // 45 rows x 12 floats
  __shared__ float cs[NC];
  __shared__ float wred[6];
  int bx = blockIdx.x;
  int r = bx >> 2, s = bx & 3;            // RSPLIT == 4
  int b0 = s * BCHUNK;
  int t = threadIdx.x;
  float* Hs = (float*)Hs4;
  if (t < NC) cs[t] = wsf[WS_COEF + r * NC + t];
  __syncthreads();
  const float LOGM = -4.0482054576f;      // log(2*pi/360)
  for (int p = t; p < BCHUNK * 9; p += 384) {
    int b = p / 9, jj = p % 9;
    int bg = b0 + b;
    int n = c_h_cnt[jj];
    float acc = 0.f;
    for (int q = 0; q < n; q++) { int c = c_h_idx[jj][q]; acc += cs[c] * wsf[WS_Q + bg * NC + c]; }
    if (jj == 0) acc += logf(qw[bg]) + LOGM;   // fold log-measure into the m=0 term
    Hs[b * 12 + jj] = acc;
  }
  __syncthreads();
  int a = t;
  float c1 = 0, c2 = 0, c3 = 0, c4 = 0, s1 = 0, s2 = 0, s3 = 0, s4 = 0;
  bool act = a < NA;
  if (act) {
    float al = alpha_grid[a];
    sincosf(al, &s1, &c1);
    sincosf(2.f * al, &s2, &c2);
    sincosf(3.f * al, &s3, &c3);
    sincosf(4.f * al, &s4, &c4);
  }
  float acc = 0.f;
#pragma unroll 5
  for (int b = 0; b < BCHUNK; b++) {
    float4 h0 = Hs4[b * 3 + 0], h1 = Hs4[b * 3 + 1], h2 = Hs4[b * 3 + 2];
    float f = h0.x + h0.y * c1 + h0.z * c2 + h0.w * c3 + h1.x * c4
            + h1.y * s1 + h1.z * s2 + h1.w * s3 + h2.x * s4;
    acc += act ? __expf(f) : 0.f;
  }
  for (int off = 32; off; off >>= 1) acc += __shfl_down(acc, off);
  int wid = t >> 6, lane = t & 63;
  if (lane == 0) wred[wid] = acc;
  __syncthreads();
  if (t == 0) {
    float ss = 0.f;
    for (int w = 0; w < 6; w++) ss += wred[w];
    wsf[WS_LRP + bx] = ss;
  }
}

// ---------------- K7: radial softmax + categorical sample + Hr ----------------
__global__ __launch_bounds__(256) void k_radial_sample(float* __restrict__ out,
                                                       float* __restrict__ wsf) {
  __shared__ float ssh[NR], lrsh[NR];
  __shared__ float wr[4]; __shared__ int wi[4];
  __shared__ float Ssh; __shared__ int rsh;
  int t = threadIdx.x;
  const uint32_t* wu = (const uint32_t*)wsf;
  uint32_t kr0 = wu[WS_KEYS + 0], kr1 = wu[WS_KEYS + 1];
  for (int i = t; i < NR; i += 256) {
    float s = wsf[WS_LRP + i * 4] + wsf[WS_LRP + i * 4 + 1]
            + wsf[WS_LRP + i * 4 + 2] + wsf[WS_LRP + i * 4 + 3];
    ssh[i] = s;
    lrsh[i] = logf(s);
  }
  __syncthreads();
  // total mass S
  float ss = 0.f;
  for (int i = t; i < NR; i += 256) ss += ssh[i];
  for (int off = 32; off; off >>= 1) ss += __shfl_down(ss, off);
  if ((t & 63) == 0) wr[t >> 6] = ss;
  __syncthreads();
  if (t == 0) Ssh = wr[0] + wr[1] + wr[2] + wr[3];
  __syncthreads();
  float S = Ssh;
  for (int i = t; i < NR; i += 256) out[O_RAD + i] = ssh[i] / S;
  // gumbel-argmax categorical over log_radial
  float bv = -INFINITY; int bi = 1 << 30;
  for (int i = t; i < NR; i += 256) {
    float v = lrsh[i] + gumbel32(kr0, kr1, (uint32_t)i);
    if (v > bv || (v == bv && i < bi)) { bv = v; bi = i; }
  }
  for (int off = 32; off; off >>= 1) {
    float v2 = __shfl_down(bv, off); int i2 = __shfl_down(bi, off);
    if (v2 > bv || (v2 == bv && i2 < bi)) { bv = v2; bi = i2; }
  }
  if ((t & 63) == 0) { wr[t >> 6] = bv; wi[t >> 6] = bi; }
  __syncthreads();
  if (t == 0) {
    float v0 = wr[0]; int i0 = wi[0];
    for (int w = 1; w < 4; w++)
      if (wr[w] > v0 || (wr[w] == v0 && wi[w] < i0)) { v0 = wr[w]; i0 = wi[w]; }
    rsh = i0;
    ((int*)wsf)[WS_RIDX] = i0;
    out[O_RADIUS] = (float)(i0 + 1) * 0.05f;
  }
  __syncthreads();
  int r = rsh;
  for (int p = t; p < NB * 9; p += 256) {
    int b = p / 9, jj = p % 9, n = c_h_cnt[jj];
    float acc = 0.f;
    for (int q = 0; q < n; q++) {
      int c = c_h_idx[jj][q];
      acc += wsf[WS_COEF + r * NC + c] * wsf[WS_Q + b * NC + c];
    }
    wsf[WS_HR + b * 12 + jj] = acc;   // NOTE: no log-measure folded here
  }
}

// ---------------- K8a: writes unnormalized exp(f); per-beta Z and gumbel-argmax ----------------
__global__ __launch_bounds__(384) void k_ang_partial(const float* __restrict__ qw,
    const float* __restrict__ alpha_grid, float* __restrict__ out, float* __restrict__ wsf) {
  __shared__ float wred[6]; __shared__ float wrv[6]; __shared__ int wri[6];
  int b = blockIdx.x, t = threadIdx.x;
  const uint32_t* wu = (const uint32_t*)wsf;
  uint32_t ka0 = wu[WS_KEYS + 2], ka1 = wu[WS_KEYS + 3];
  const float4* hr4 = (const float4*)(wsf + WS_HR + b * 12);
  float4 h0 = hr4[0], h1 = hr4[1], h2 = hr4[2];
  const float MEAS = 0.01745329252f;            // 2*pi/360
  float elm = qw[b] * MEAS;                     // exp(log_meas[b]) exactly
  float lm = logf(elm);
  float e = 0.f, v = -INFINITY; int idx = b * NA + t;
  if (t < NA) {
    float al = alpha_grid[t];
    float s1, c1, s2, c2, s3, c3, s4, c4;
    sincosf(al, &s1, &c1); sincosf(2.f * al, &s2, &c2);
    sincosf(3.f * al, &s3, &c3); sincosf(4.f * al, &s4, &c4);
    float f = h0.x + h0.y * c1 + h0.z * c2 + h0.w * c3 + h1.x * c4
            + h1.y * s1 + h1.z * s2 + h1.w * s3 + h2.x * s4;
    float ef = __expf(f);
    out[O_ANG + idx] = ef;                      // unnormalized; scaled by 1/Z later
    e = ef * elm;                               // exp(f + lm)
    v = f + lm + gumbel32(ka0, ka1, (uint32_t)idx);
  }
  int wid = t >> 6, lane = t & 63;
  for (int off = 32; off; off >>= 1) e += __shfl_down(e, off);
  if (lane == 0) wred[wid] = e;
  for (int off = 32; off; off >>= 1) {
    float v2 = __shfl_down(v, off); int i2 = __shfl_down(idx, off);
    if (v2 > v || (v2 == v && i2 < idx)) { v = v2; idx = i2; }
  }
  if (lane == 0) { wrv[wid] = v; wri[wid] = idx; }
  __syncthreads();
  if (t == 0) {
    float zs = 0.f;
    float v0 = wrv[0]; int i0 = wri[0];
    for (int w = 0; w < 6; w++) {
      zs += wred[w];
      if (w && (wrv[w] > v0 || (wrv[w] == v0 && wri[w] < i0))) { v0 = wrv[w]; i0 = wri[w]; }
    }
    wsf[WS_PSUM + b] = zs;
    wsf[WS_PV + b] = v0;
    ((int*)wsf)[WS_PI + b] = i0;
  }
}

// ---------------- K8b: invZ + final angular argmax -> y/alpha outputs ----------------
__global__ __launch_bounds__(256) void k_ang_final(const float* __restrict__ y_grid,
    const float* __restrict__ alpha_grid, float* __restrict__ out, float* __restrict__ wsf) {
  __shared__ float wr[4]; __shared__ int wi[4];
  int t = threadIdx.x;
  float sv = (t < NB) ? wsf[WS_PSUM + t] : 0.f;
  for (int off = 32; off; off >>= 1) sv += __shfl_down(sv, off);
  if ((t & 63) == 0) wr[t >> 6] = sv;
  __syncthreads();
  if (t == 0) wsf[WS_INVZ] = 1.0f / (wr[0] + wr[1] + wr[2] + wr[3]);
  __syncthreads();
  float v = (t < NB) ? wsf[WS_PV + t] : -INFINITY;
  int i = (t < NB) ? ((const int*)wsf)[WS_PI + t] : (1 << 30);
  for (int off = 32; off; off >>= 1) {
    float v2 = __shfl_down(v, off); int i2 = __shfl_down(i, off);
    if (v2 > v || (v2 == v && i2 < i)) { v = v2; i = i2; }
  }
  if ((t & 63) == 0) { wr[t >> 6] = v; wi[t >> 6] = i; }
  __syncthreads();
  if (t == 0) {
    float v0 = wr[0]; int i0 = wi[0];
    for (int w = 1; w < 4; w++)
      if (wr[w] > v0 || (wr[w] == v0 && wi[w] < i0)) { v0 = wr[w]; i0 = wi[w]; }
    int yi = i0 / NA, ai = i0 % NA;
    out[O_Y] = y_grid[yi];
    out[O_ALPHA] = alpha_grid[ai];
  }
}

// ---------------- K8c: scale angular block by 1/Z ----------------
__global__ __launch_bounds__(256) void k_ang_scale(float* __restrict__ out,
                                                   const float* __restrict__ wsf) {
  int i = blockIdx.x * 256 + threadIdx.x;
  float invZ = wsf[WS_INVZ];
  if (i < NB * NA) out[O_ANG + i] *= invZ;
}

// ---------------- launch ----------------
extern "C" void kernel_launch(void* const* d_in, const int* in_sizes, int n_in,
                              void* d_out, int out_size, void* d_ws, size_t ws_size,
                              hipStream_t stream) {
  const float* x          = (const float*)d_in[0];
  const float* fw1        = (const float*)d_in[1];
  const float* fw2        = (const float*)d_in[2];
  const float* fw3        = (const float*)d_in[3];
  const float* fw4        = (const float*)d_in[4];
  const float* fw5        = (const float*)d_in[5];
  const float* tw1        = (const float*)d_in[6];
  const float* tw2        = (const float*)d_in[7];
  const float* tw3        = (const float*)d_in[8];
  const float* tw4        = (const float*)d_in[9];
  const float* tw5        = (const float*)d_in[10];
  const float* tw6        = (const float*)d_in[11];
  const float* pos_w      = (const float*)d_in[12];
  const float* type_emb   = (const float*)d_in[13];
  const float* basis      = (const float*)d_in[14];
  const float* qw         = (const float*)d_in[15];
  const float* y_grid     = (const float*)d_in[16];
  const float* alpha_grid = (const float*)d_in[17];
  (void)in_sizes; (void)n_in; (void)out_size; (void)ws_size;
  float* out = (float*)d_out;
  float* wsf = (float*)d_ws;

  k_front<<<NNODES + 36, 128, 0, stream>>>(x, fw1, fw2, fw3, fw4, fw5, basis, alpha_grid, wsf);
  k_type<<<1, 128, 0, stream>>>(x, tw1, tw2, tw3, tw4, tw5, tw6, type_emb, out, wsf);
  k_coeffs<<<(NR * NC + 63) / 64, 256, 0, stream>>>(pos_w, wsf);
  k_radial_lse<<<NR * RSPLIT, 384, 0, stream>>>(qw, alpha_grid, wsf);
  k_radial_sample<<<1, 256, 0, stream>>>(out, wsf);
  k_ang_partial<<<NB, 384, 0, stream>>>(qw, alpha_grid, out, wsf);
  k_ang_final<<<1, 256, 0, stream>>>(y_grid, alpha_grid, out, wsf);
  k_ang_scale<<<(NB * NA + 255) / 256, 256, 0, stream>>>(out, wsf);
}

// Round 3
// 65.842 us; speedup vs baseline: 1.6874x; 1.1379x over previous
//
#include <hip/hip_runtime.h>
#include <math.h>
#include <stdint.h>

// ---------------- problem constants ----------------
#define NNODES 512
#define FEAT   128
#define NR     300
#define NC     25
#define NB     180
#define NA     360
#define RSPLIT 4
#define BCHUNK (NB / RSPLIT)   // 45
// output layout: type_dist[6] | radial_probs[300] | angular[64800] | radius | y | alpha
#define O_TYPE   0
#define O_RAD    6
#define O_ANG    306
#define O_RADIUS 65106
#define O_Y      65107
#define O_ALPHA  65108

// ---------------- workspace layout (float indices) ----------------
#define WS_KEYS   0     // 4 uints: k_r(2), k_a(2)
#define WS_FOCUS  4     // int
#define WS_TYPEI  5     // int
#define WS_RIDX   6     // int
#define WS_INVZ   7     // float (1/Z of angular dist)
#define WS_DEAD   8     // dead slot for prefetch dummy-use
#define WS_SCORES 320   // 512
#define WS_POSIN  832   // 256
#define WS_PSUM   1088  // 180
#define WS_PV     1280  // 180
#define WS_PI     1472  // 180 ints
#define WS_Q      1664  // 180*25 = 4500
#define WS_HR     6176  // 180*12 = 2160 (16B aligned)
#define WS_COEF   8352  // 7500
#define WS_LRP    15872 // 300*4 partial sphere sums
// total ~17072 floats (~68 KB)

// grid split for k_front
#define GB_MLP   NNODES                  // 512 focus-MLP blocks
#define GB_PREP  36                      // Q extraction (36*128 >= 4500)
#define GB_PFT   162                     // type-weight prefetch (162*512 floats >= 82688)
#define GB_PFP   768                     // pos_w prefetch
#define GB_TOTAL (GB_MLP + GB_PREP + GB_PFT + GB_PFP)

// m value per SH column c (l = 0..4, m = -l..l, c = l*l + l + m)
__constant__ int c_m_of_c[25] = {0,-1,0,1,-2,-1,0,1,2,-3,-2,-1,0,1,2,3,-4,-3,-2,-1,0,1,2,3,4};
// Fourier-coefficient term lists: jj=0..4 -> cos m=0..4 ; jj=5..8 -> sin m=1..4
__constant__ int c_h_cnt[9] = {5,4,3,2,1,4,3,2,1};
__constant__ int c_h_idx[9][5] = {
  {0,2,6,12,20},
  {3,7,13,21,0},
  {8,14,22,0,0},
  {15,23,0,0,0},
  {24,0,0,0,0},
  {1,5,11,19,0},
  {4,10,18,0,0},
  {9,17,0,0,0},
  {16,0,0,0,0}};

// ---------------- threefry2x32 (JAX semantics) ----------------
__device__ __forceinline__ void tf2x32(uint32_t k0, uint32_t k1, uint32_t x0, uint32_t x1,
                                       uint32_t& o0, uint32_t& o1) {
  uint32_t ks2 = k0 ^ k1 ^ 0x1BD11BDAu;
#define TF_RND(r) { x0 += x1; x1 = (x1 << r) | (x1 >> (32 - r)); x1 ^= x0; }
  x0 += k0; x1 += k1;
  TF_RND(13) TF_RND(15) TF_RND(26) TF_RND(6)
  x0 += k1; x1 += ks2 + 1u;
  TF_RND(17) TF_RND(29) TF_RND(16) TF_RND(24)
  x0 += ks2; x1 += k0 + 2u;
  TF_RND(13) TF_RND(15) TF_RND(26) TF_RND(6)
  x0 += k0; x1 += k1 + 3u;
  TF_RND(17) TF_RND(29) TF_RND(16) TF_RND(24)
  x0 += k1; x1 += ks2 + 4u;
  TF_RND(13) TF_RND(15) TF_RND(26) TF_RND(6)
  x0 += ks2; x1 += k0 + 5u;
#undef TF_RND
  o0 = x0; o1 = x1;
}

// partitionable-mode 32-bit random bits for 64-bit counter (hi=0, lo=i): word0 ^ word1
__device__ __forceinline__ float gumbel32(uint32_t k0, uint32_t k1, uint32_t lo) {
  uint32_t o0, o1; tf2x32(k0, k1, 0u, lo, o0, o1);
  uint32_t bits = o0 ^ o1;
  float u = __uint_as_float((bits >> 9) | 0x3f800000u) - 1.0f;   // [0,1)
  u = fmaxf(u, 1.1754944e-38f);                                   // minval = tiny
  return -logf(-logf(u));
}

// ---------------- K1: focus MLP + prep + weight prefetch (block-role split) ----------------
__global__ __launch_bounds__(128) void k_front(const float* __restrict__ x,
    const float* __restrict__ w1, const float* __restrict__ w2, const float* __restrict__ w3,
    const float* __restrict__ w4, const float* __restrict__ w5,
    const float* __restrict__ basis, const float* __restrict__ alpha_grid,
    const float* __restrict__ tw1, const float* __restrict__ tw2, const float* __restrict__ tw3,
    const float* __restrict__ tw4, const float* __restrict__ tw5, const float* __restrict__ tw6,
    const float* __restrict__ pos_w,
    float* __restrict__ wsf) {
  int bx = blockIdx.x;
  if (bx >= GB_MLP + GB_PREP + GB_PFT) {
    // ---- pos_w prefetch into L3 ----
    int pb = bx - (GB_MLP + GB_PREP + GB_PFT);
    const float4* p4 = (const float4*)pos_w;
    const int n4 = NR * NC * 256 / 4;          // 480000
    float acc = 0.f;
    for (int i = pb * 128 + threadIdx.x; i < n4; i += GB_PFP * 128) {
      float4 v = p4[i];
      acc += v.x + v.y + v.z + v.w;
    }
    if (acc == -1.2345678e30f) wsf[WS_DEAD] = acc;   // never true; defeats DCE
    return;
  }
  if (bx >= GB_MLP + GB_PREP) {
    // ---- type-weight prefetch into L3 ----
    int pb = bx - (GB_MLP + GB_PREP);
    int base = pb * 128;                        // float4 index within a 4096-float4 matrix
    float acc = 0.f;
    int i = base + threadIdx.x;
    // tw1..tw5: 16384 floats = 4096 float4 each; covered by pb 0..31 each
    const float4* mats[5] = {(const float4*)tw1, (const float4*)tw2, (const float4*)tw3,
                             (const float4*)tw4, (const float4*)tw5};
    int mi = pb >> 5;                           // 0..4 for pb<160
    if (mi < 5) {
      int li = (pb & 31) * 128 + threadIdx.x;   // 0..4095
      float4 v = mats[mi][li];
      acc += v.x + v.y + v.z + v.w;
    } else {
      // tw6: 768 floats = 192 float4
      int li = (pb - 160) * 128 + threadIdx.x;
      if (li < 192) { float4 v = ((const float4*)tw6)[li]; acc += v.x + v.y + v.z + v.w; }
    }
    (void)i;
    if (acc == -1.2345678e30f) wsf[WS_DEAD] = acc;
    return;
  }
  if (bx >= GB_MLP) {
    // ---- prep role: Q extraction + PRNG keys ----
    int t = (bx - GB_MLP) * 128 + threadIdx.x;
    if (bx == GB_MLP && threadIdx.x == 0) {
      uint32_t* wu = (uint32_t*)wsf;
      uint32_t o0, o1;
      tf2x32(0u, 42u, 0u, 0u, o0, o1); wu[WS_KEYS + 0] = o0; wu[WS_KEYS + 1] = o1; // k_r
      tf2x32(0u, 42u, 0u, 1u, o0, o1); wu[WS_KEYS + 2] = o0; wu[WS_KEYS + 3] = o1; // k_a
    }
    if (t < NB * NC) {
      int b = t / NC, c = t % NC;
      int m = c_m_of_c[c];
      float q;
      if (m >= 0) {
        q = basis[(b * NA + 0) * NC + c];                 // cos(0)=1
      } else {
        float a10 = alpha_grid[10];
        q = basis[(b * NA + 10) * NC + c] / sinf((float)(-m) * a10);
      }
      wsf[WS_Q + t] = q;
    }
    return;
  }
  // ---- focus MLP role ----
  __shared__ float ha[128], hb[128];
  int n = bx, j = threadIdx.x;
  ha[j] = x[n * FEAT + j];
  __syncthreads();
  float acc = 0.f;
#pragma unroll 8
  for (int k = 0; k < 128; k++) acc += ha[k] * w1[k * 128 + j];
  hb[j] = fmaxf(acc, 0.f);
  __syncthreads();
  acc = 0.f;
#pragma unroll 8
  for (int k = 0; k < 128; k++) acc += hb[k] * w2[k * 128 + j];
  ha[j] = fmaxf(acc, 0.f);
  __syncthreads();
  if (j < 64) {
    acc = 0.f;
#pragma unroll 8
    for (int k = 0; k < 128; k++) acc += ha[k] * w3[k * 64 + j];
    hb[j] = fmaxf(acc, 0.f);
  }
  __syncthreads();
  if (j < 16) {
    acc = 0.f;
#pragma unroll
    for (int k = 0; k < 64; k++) acc += hb[k] * w4[k * 16 + j];
    ha[j] = fmaxf(acc, 0.f);
  }
  __syncthreads();
  if (j == 0) {
    acc = 0.f;
#pragma unroll
    for (int k = 0; k < 16; k++) acc += ha[k] * w5[k * 2 + 0];
    wsf[WS_SCORES + n] = acc;
  }
}

// ---------------- K3: focus argmax + type MLP (softplus), 1024 threads ----------------
__global__ __launch_bounds__(1024) void k_type(const float* __restrict__ x,
    const float* __restrict__ w1, const float* __restrict__ w2, const float* __restrict__ w3,
    const float* __restrict__ w4, const float* __restrict__ w5, const float* __restrict__ w6,
    const float* __restrict__ type_emb, float* __restrict__ out, float* __restrict__ wsf) {
  __shared__ float src[128];
  __shared__ float partial[8][128];
  __shared__ float wrv[16]; __shared__ int wri[16];
  __shared__ float lg[6];
  __shared__ int f_sh, ti_sh;
  int t = threadIdx.x;
  int lane = t & 63, wid = t >> 6;
  // ---- argmax over 513 (scores ++ [0]) ----
  float bv = -INFINITY; int bi = 1 << 30;
  if (t < NNODES + 1) { bv = (t < NNODES) ? wsf[WS_SCORES + t] : 0.f; bi = t; }
  for (int off = 32; off; off >>= 1) {
    float v2 = __shfl_down(bv, off); int i2 = __shfl_down(bi, off);
    if (v2 > bv || (v2 == bv && i2 < bi)) { bv = v2; bi = i2; }
  }
  if (lane == 0) { wrv[wid] = bv; wri[wid] = bi; }
  __syncthreads();
  if (t == 0) {
    float v0 = wrv[0]; int i0 = wri[0];
    for (int w = 1; w < 16; w++)
      if (wrv[w] > v0 || (wrv[w] == v0 && wri[w] < i0)) { v0 = wrv[w]; i0 = wri[w]; }
    int focus = (i0 < NNODES - 1) ? i0 : (NNODES - 1);
    ((int*)wsf)[WS_FOCUS] = focus;
    f_sh = focus;
  }
  __syncthreads();
  int focus = f_sh;
  if (t < 128) { float xv = x[focus * FEAT + t]; src[t] = xv; wsf[WS_POSIN + t] = xv; }
  __syncthreads();
  // ---- 5 softplus layers, K split 8 ways ----
  const float* Ws[5] = {w1, w2, w3, w4, w5};
#pragma unroll
  for (int L = 0; L < 5; L++) {
    const float* W = Ws[L];
    int j = t & 127, kc = t >> 7;
    float acc = 0.f;
#pragma unroll
    for (int k = 0; k < 16; k++) acc += src[kc * 16 + k] * W[(kc * 16 + k) * 128 + j];
    partial[kc][j] = acc;
    __syncthreads();
    if (t < 128) {
      float s = 0.f;
#pragma unroll
      for (int q = 0; q < 8; q++) s += partial[q][t];
      src[t] = fmaxf(s, 0.f) + log1pf(expf(-fabsf(s)));  // softplus
    }
    __syncthreads();
  }
  // ---- w6 head: 6 outputs, 128 k each; threads t<768 ----
  float prod = 0.f;
  if (t < 768) { int o = t >> 7, j = t & 127; prod = src[j] * w6[j * 6 + o]; }
  for (int off = 32; off; off >>= 1) prod += __shfl_down(prod, off);
  if (t < 768 && lane == 0) wrv[wid] = prod;    // wid = 2*o (+1)
  __syncthreads();
  if (t == 0) {
    for (int o = 0; o < 6; o++) lg[o] = wrv[2 * o] + wrv[2 * o + 1];
    float M = lg[0]; int am = 0;
    for (int i = 1; i < 6; i++) if (lg[i] > M) { M = lg[i]; am = i; }
    float e[6], S = 0.f;
    for (int i = 0; i < 6; i++) { e[i] = expf(lg[i] - M); S += e[i]; }
    for (int i = 0; i < 6; i++) out[O_TYPE + i] = e[i] / S;
    int ti = (am < 4) ? am : 4;
    ((int*)wsf)[WS_TYPEI] = ti;
    ti_sh = ti;
  }
  __syncthreads();
  if (t < 128) wsf[WS_POSIN + 128 + t] = type_emb[ti_sh * FEAT + t];
}

// ---------------- K4: coeffs = pos_in @ pos_w (split-K, 64 outputs/block) ----------------
__global__ __launch_bounds__(256) void k_coeffs(const float* __restrict__ pos_w,
                                                float* __restrict__ wsf) {
  __shared__ float pin[256];
  __shared__ float partial[4][64];
  int t = threadIdx.x;
  pin[t] = wsf[WS_POSIN + t];
  __syncthreads();
  int oL = t & 63, kc = t >> 6;
  int o = blockIdx.x * 64 + oL;
  float acc = 0.f;
  if (o < NR * NC) {
#pragma unroll 16
    for (int k = 0; k < 64; k++) acc += pin[kc * 64 + k] * pos_w[(kc * 64 + k) * (NR * NC) + o];
  }
  partial[kc][oL] = acc;
  __syncthreads();
  if (kc == 0 && o < NR * NC)
    wsf[WS_COEF + o] = partial[0][oL] + partial[1][oL] + partial[2][oL] + partial[3][oL];
}

// ---------------- K6: per-(radius, beta-chunk) partial sphere sum ----------------
__global__ __launch_bounds__(384) void k_radial_lse(const float* __restrict__ qw,
    const float* __restrict__ alpha_grid, float* __restrict__ wsf) {
  __shared__ float4 Hs4[BCHUNK * 3];      // 45 rows x 12 floats
  __shared__ float cs[NC];
  __shared__ float wred[6];
  int bx = blockIdx.x;
  int r = bx >> 2, s = bx & 3;            // RSPLIT == 4
  int b0 = s * BCHUNK;
  int t = threadIdx.x;
  float* Hs = (float*)Hs4;
  if (t < NC) cs[t] = wsf[WS_COEF + r * NC + t];
  __syncthreads();
  const float LOGM = -4.0482054576f;      // log(2*pi/360)
  for (int p = t; p < BCHUNK * 9; p += 384) {
    int b = p / 9, jj = p % 9;
    int bg = b0 + b;
    int n = c_h_cnt[jj];
    float acc = 0.f;
    for (int q = 0; q < n; q++) { int c = c_h_idx[jj][q]; acc += cs[c] * wsf[WS_Q + bg * NC + c]; }
    if (jj == 0) acc += logf(qw[bg]) + LOGM;   // fold log-measure into the m=0 term
    Hs[b * 12 + jj] = acc;
  }
  __syncthreads();
  int a = t;
  float c1 = 0, c2 = 0, c3 = 0, c4 = 0, s1 = 0, s2 = 0, s3 = 0, s4 = 0;
  bool act = a < NA;
  if (act) {
    float al = alpha_grid[a];
    sincosf(al, &s1, &c1);
    sincosf(2.f * al, &s2, &c2);
    sincosf(3.f * al, &s3, &c3);
    sincosf(4.f * al, &s4, &c4);
  }
  float acc = 0.f;
#pragma unroll 5
  for (int b = 0; b < BCHUNK; b++) {
    float4 h0 = Hs4[b * 3 + 0], h1 = Hs4[b * 3 + 1], h2 = Hs4[b * 3 + 2];
    float f = h0.x + h0.y * c1 + h0.z * c2 + h0.w * c3 + h1.x * c4
            + h1.y * s1 + h1.z * s2 + h1.w * s3 + h2.x * s4;
    acc += act ? __expf(f) : 0.f;
  }
  for (int off = 32; off; off >>= 1) acc += __shfl_down(acc, off);
  int wid = t >> 6, lane = t & 63;
  if (lane == 0) wred[wid] = acc;
  __syncthreads();
  if (t == 0) {
    float ss = 0.f;
    for (int w = 0; w < 6; w++) ss += wred[w];
    wsf[WS_LRP + bx] = ss;
  }
}

// ---------------- K7: radial softmax + categorical sample + Hr ----------------
__global__ __launch_bounds__(256) void k_radial_sample(float* __restrict__ out,
                                                       float* __restrict__ wsf) {
  __shared__ float ssh[NR], lrsh[NR];
  __shared__ float wr[4]; __shared__ int wi[4];
  __shared__ float Ssh; __shared__ int rsh;
  int t = threadIdx.x;
  const uint32_t* wu = (const uint32_t*)wsf;
  uint32_t kr0 = wu[WS_KEYS + 0], kr1 = wu[WS_KEYS + 1];
  for (int i = t; i < NR; i += 256) {
    float s = wsf[WS_LRP + i * 4] + wsf[WS_LRP + i * 4 + 1]
            + wsf[WS_LRP + i * 4 + 2] + wsf[WS_LRP + i * 4 + 3];
    ssh[i] = s;
    lrsh[i] = logf(s);
  }
  __syncthreads();
  // total mass S
  float ss = 0.f;
  for (int i = t; i < NR; i += 256) ss += ssh[i];
  for (int off = 32; off; off >>= 1) ss += __shfl_down(ss, off);
  if ((t & 63) == 0) wr[t >> 6] = ss;
  __syncthreads();
  if (t == 0) Ssh = wr[0] + wr[1] + wr[2] + wr[3];
  __syncthreads();
  float S = Ssh;
  for (int i = t; i < NR; i += 256) out[O_RAD + i] = ssh[i] / S;
  // gumbel-argmax categorical over log_radial
  float bv = -INFINITY; int bi = 1 << 30;
  for (int i = t; i < NR; i += 256) {
    float v = lrsh[i] + gumbel32(kr0, kr1, (uint32_t)i);
    if (v > bv || (v == bv && i < bi)) { bv = v; bi = i; }
  }
  for (int off = 32; off; off >>= 1) {
    float v2 = __shfl_down(bv, off); int i2 = __shfl_down(bi, off);
    if (v2 > bv || (v2 == bv && i2 < bi)) { bv = v2; bi = i2; }
  }
  if ((t & 63) == 0) { wr[t >> 6] = bv; wi[t >> 6] = bi; }
  __syncthreads();
  if (t == 0) {
    float v0 = wr[0]; int i0 = wi[0];
    for (int w = 1; w < 4; w++)
      if (wr[w] > v0 || (wr[w] == v0 && wi[w] < i0)) { v0 = wr[w]; i0 = wi[w]; }
    rsh = i0;
    ((int*)wsf)[WS_RIDX] = i0;
    out[O_RADIUS] = (float)(i0 + 1) * 0.05f;
  }
  __syncthreads();
  int r = rsh;
  for (int p = t; p < NB * 9; p += 256) {
    int b = p / 9, jj = p % 9, n = c_h_cnt[jj];
    float acc = 0.f;
    for (int q = 0; q < n; q++) {
      int c = c_h_idx[jj][q];
      acc += wsf[WS_COEF + r * NC + c] * wsf[WS_Q + b * NC + c];
    }
    wsf[WS_HR + b * 12 + jj] = acc;   // NOTE: no log-measure folded here
  }
}

// ---------------- K8a: writes unnormalized exp(f); per-beta Z and gumbel-argmax ----------------
__global__ __launch_bounds__(384) void k_ang_partial(const float* __restrict__ qw,
    const float* __restrict__ alpha_grid, float* __restrict__ out, float* __restrict__ wsf) {
  __shared__ float wred[6]; __shared__ float wrv[6]; __shared__ int wri[6];
  int b = blockIdx.x, t = threadIdx.x;
  const uint32_t* wu = (const uint32_t*)wsf;
  uint32_t ka0 = wu[WS_KEYS + 2], ka1 = wu[WS_KEYS + 3];
  const float4* hr4 = (const float4*)(wsf + WS_HR + b * 12);
  float4 h0 = hr4[0], h1 = hr4[1], h2 = hr4[2];
  const float MEAS = 0.01745329252f;            // 2*pi/360
  float elm = qw[b] * MEAS;                     // exp(log_meas[b]) exactly
  float lm = logf(elm);
  float e = 0.f, v = -INFINITY; int idx = b * NA + t;
  if (t < NA) {
    float al = alpha_grid[t];
    float s1, c1, s2, c2, s3, c3, s4, c4;
    sincosf(al, &s1, &c1); sincosf(2.f * al, &s2, &c2);
    sincosf(3.f * al, &s3, &c3); sincosf(4.f * al, &s4, &c4);
    float f = h0.x + h0.y * c1 + h0.z * c2 + h0.w * c3 + h1.x * c4
            + h1.y * s1 + h1.z * s2 + h1.w * s3 + h2.x * s4;
    float ef = __expf(f);
    out[O_ANG + idx] = ef;                      // unnormalized; scaled by 1/Z later
    e = ef * elm;                               // exp(f + lm)
    v = f + lm + gumbel32(ka0, ka1, (uint32_t)idx);
  }
  int wid = t >> 6, lane = t & 63;
  for (int off = 32; off; off >>= 1) e += __shfl_down(e, off);
  if (lane == 0) wred[wid] = e;
  for (int off = 32; off; off >>= 1) {
    float v2 = __shfl_down(v, off); int i2 = __shfl_down(idx, off);
    if (v2 > v || (v2 == v && i2 < idx)) { v = v2; idx = i2; }
  }
  if (lane == 0) { wrv[wid] = v; wri[wid] = idx; }
  __syncthreads();
  if (t == 0) {
    float zs = 0.f;
    float v0 = wrv[0]; int i0 = wri[0];
    for (int w = 0; w < 6; w++) {
      zs += wred[w];
      if (w && (wrv[w] > v0 || (wrv[w] == v0 && wri[w] < i0))) { v0 = wrv[w]; i0 = wri[w]; }
    }
    wsf[WS_PSUM + b] = zs;
    wsf[WS_PV + b] = v0;
    ((int*)wsf)[WS_PI + b] = i0;
  }
}

// ---------------- K8b: invZ + final angular argmax -> y/alpha outputs ----------------
__global__ __launch_bounds__(256) void k_ang_final(const float* __restrict__ y_grid,
    const float* __restrict__ alpha_grid, float* __restrict__ out, float* __restrict__ wsf) {
  __shared__ float wr[4]; __shared__ int wi[4];
  int t = threadIdx.x;
  float sv = (t < NB) ? wsf[WS_PSUM + t] : 0.f;
  for (int off = 32; off; off >>= 1) sv += __shfl_down(sv, off);
  if ((t & 63) == 0) wr[t >> 6] = sv;
  __syncthreads();
  if (t == 0) wsf[WS_INVZ] = 1.0f / (wr[0] + wr[1] + wr[2] + wr[3]);
  __syncthreads();
  float v = (t < NB) ? wsf[WS_PV + t] : -INFINITY;
  int i = (t < NB) ? ((const int*)wsf)[WS_PI + t] : (1 << 30);
  for (int off = 32; off; off >>= 1) {
    float v2 = __shfl_down(v, off); int i2 = __shfl_down(i, off);
    if (v2 > v || (v2 == v && i2 < i)) { v = v2; i = i2; }
  }
  if ((t & 63) == 0) { wr[t >> 6] = v; wi[t >> 6] = i; }
  __syncthreads();
  if (t == 0) {
    float v0 = wr[0]; int i0 = wi[0];
    for (int w = 1; w < 4; w++)
      if (wr[w] > v0 || (wr[w] == v0 && wi[w] < i0)) { v0 = wr[w]; i0 = wi[w]; }
    int yi = i0 / NA, ai = i0 % NA;
    out[O_Y] = y_grid[yi];
    out[O_ALPHA] = alpha_grid[ai];
  }
}

// ---------------- K8c: scale angular block by 1/Z ----------------
__global__ __launch_bounds__(256) void k_ang_scale(float* __restrict__ out,
                                                   const float* __restrict__ wsf) {
  int i = blockIdx.x * 256 + threadIdx.x;
  float invZ = wsf[WS_INVZ];
  if (i < NB * NA) out[O_ANG + i] *= invZ;
}

// ---------------- launch ----------------
extern "C" void kernel_launch(void* const* d_in, const int* in_sizes, int n_in,
                              void* d_out, int out_size, void* d_ws, size_t ws_size,
                              hipStream_t stream) {
  const float* x          = (const float*)d_in[0];
  const float* fw1        = (const float*)d_in[1];
  const float* fw2        = (const float*)d_in[2];
  const float* fw3        = (const float*)d_in[3];
  const float* fw4        = (const float*)d_in[4];
  const float* fw5        = (const float*)d_in[5];
  const float* tw1        = (const float*)d_in[6];
  const float* tw2        = (const float*)d_in[7];
  const float* tw3        = (const float*)d_in[8];
  const float* tw4        = (const float*)d_in[9];
  const float* tw5        = (const float*)d_in[10];
  const float* tw6        = (const float*)d_in[11];
  const float* pos_w      = (const float*)d_in[12];
  const float* type_emb   = (const float*)d_in[13];
  const float* basis      = (const float*)d_in[14];
  const float* qw         = (const float*)d_in[15];
  const float* y_grid     = (const float*)d_in[16];
  const float* alpha_grid = (const float*)d_in[17];
  (void)in_sizes; (void)n_in; (void)out_size; (void)ws_size;
  float* out = (float*)d_out;
  float* wsf = (float*)d_ws;

  k_front<<<GB_TOTAL, 128, 0, stream>>>(x, fw1, fw2, fw3, fw4, fw5, basis, alpha_grid,
                                        tw1, tw2, tw3, tw4, tw5, tw6, pos_w, wsf);
  k_type<<<1, 1024, 0, stream>>>(x, tw1, tw2, tw3, tw4, tw5, tw6, type_emb, out, wsf);
  k_coeffs<<<(NR * NC + 63) / 64, 256, 0, stream>>>(pos_w, wsf);
  k_radial_lse<<<NR * RSPLIT, 384, 0, stream>>>(qw, alpha_grid, wsf);
  k_radial_sample<<<1, 256, 0, stream>>>(out, wsf);
  k_ang_partial<<<NB, 384, 0, stream>>>(qw, alpha_grid, out, wsf);
  k_ang_final<<<1, 256, 0, stream>>>(y_grid, alpha_grid, out, wsf);
  k_ang_scale<<<(NB * NA + 255) / 256, 256, 0, stream>>>(out, wsf);
}